// Round 9
// baseline (486.259 us; speedup 1.0000x reference)
//
#include <hip/hip_runtime.h>
#include <hip/hip_bf16.h>

#define V 49152
#define NNZ 9
#define EPSV 1e-5f
#define SLOPE 0.1f

typedef __attribute__((ext_vector_type(8))) short bf16x8;   // 8 bf16 (4 VGPRs)
typedef __attribute__((ext_vector_type(4))) float f32x4;    // MFMA C/D

__device__ __forceinline__ float lo2f(unsigned u) { return __uint_as_float(u << 16); }
__device__ __forceinline__ float hi2f(unsigned u) { return __uint_as_float(u & 0xffff0000u); }
__device__ __forceinline__ unsigned short f2us(float f) {
    __hip_bfloat16 h = __float2bfloat16(f);
    return *(unsigned short*)&h;
}
__device__ __forceinline__ float us2f(unsigned short u) { return __uint_as_float(((unsigned)u) << 16); }
__device__ __forceinline__ unsigned pk2(float a, float b) {
    return ((unsigned)f2us(a)) | (((unsigned)f2us(b)) << 16);
}

// async 16B/lane global->LDS; LDS base wave-uniform (+lane*16 auto), global addr per-lane
__device__ __forceinline__ void gload_lds16(const void* g, void* l) {
    __builtin_amdgcn_global_load_lds((__attribute__((address_space(1))) void*)g,
                                     (__attribute__((address_space(3))) void*)l, 16, 0, 0);
}

// ---- prep: convert+transpose weights to bf16 [kk][o][f]; zero GN partial buffers ----
__global__ __launch_bounds__(256) void prep_k(
    const float* __restrict__ W1, const float* __restrict__ Wr, const float* __restrict__ W2,
    unsigned short* __restrict__ Wt1, unsigned short* __restrict__ Wtr, unsigned short* __restrict__ Wt2,
    float* __restrict__ part)
{
    int i = blockIdx.x * 256 + threadIdx.x;
    if (i < 32768) {                 // Wt2[kk][o][f] = W2[kk][f][o], F=64
        int kk = i >> 12, rem = i & 4095, o = rem >> 6, f = rem & 63;
        Wt2[i] = f2us(W2[kk * 4096 + f * 64 + o]);
    } else if (i < 49152) {          // Wt1, F=32
        int j = i - 32768;
        int kk = j >> 11, rem = j & 2047, o = rem >> 5, f = rem & 31;
        Wt1[j] = f2us(W1[kk * 2048 + f * 64 + o]);
    } else if (i < 65536) {          // Wtr, F=32
        int j = i - 49152;
        int kk = j >> 11, rem = j & 2047, o = rem >> 5, f = rem & 31;
        Wtr[j] = f2us(Wr[kk * 2048 + f * 64 + o]);
    } else if (i < 66560) {
        part[i - 65536] = 0.f;
    }
}

// ---- reorder x [B,V,32] f32 -> T0 conv1 layout [V][b*32+f] bf16 (packed dwords) ----
__global__ __launch_bounds__(256) void reorder_k(const float* __restrict__ x, unsigned* __restrict__ t0) {
    int idx = blockIdx.x * 256 + threadIdx.x;   // < V*32 dwords
    int v = idx >> 5, j2 = idx & 31;
    int b = j2 >> 4, f0 = (j2 & 15) * 2;
    const float* p = x + ((size_t)b * V + v) * 32 + f0;
    t0[idx] = pk2(p[0], p[1]);
}

// ---- SpMM Chebyshev step: zn = 2*(L@zc) - zp (bf16 rows). 32B (2 uint4) per thread. ----
template<int THR, bool FIRST>
__global__ __launch_bounds__(256) void spmm_step(
    const uint4* __restrict__ zc, const uint4* __restrict__ zp, uint4* __restrict__ zn,
    const float* __restrict__ vals, const int* __restrict__ col)
{
    constexpr int L4 = THR * 2;                   // uint4 per row
    int tid = blockIdx.x * 256 + threadIdx.x;     // over V*THR
    int v = tid / THR;
    int c = (tid - v * THR) * 2;
    int base = v * NNZ;
    float t[16];
    #pragma unroll
    for (int i = 0; i < 16; ++i) t[i] = 0.f;
    #pragma unroll
    for (int n = 0; n < NNZ; ++n) {
        float a = vals[base + n];
        int cc = col[base + n];
        const uint4* p = zc + (size_t)cc * L4 + c;
        uint4 u0 = p[0];
        uint4 u1 = p[1];
        t[0] += a * lo2f(u0.x); t[1] += a * hi2f(u0.x);
        t[2] += a * lo2f(u0.y); t[3] += a * hi2f(u0.y);
        t[4] += a * lo2f(u0.z); t[5] += a * hi2f(u0.z);
        t[6] += a * lo2f(u0.w); t[7] += a * hi2f(u0.w);
        t[8]  += a * lo2f(u1.x); t[9]  += a * hi2f(u1.x);
        t[10] += a * lo2f(u1.y); t[11] += a * hi2f(u1.y);
        t[12] += a * lo2f(u1.z); t[13] += a * hi2f(u1.z);
        t[14] += a * lo2f(u1.w); t[15] += a * hi2f(u1.w);
    }
    if (!FIRST) {
        const uint4* pp = zp + (size_t)v * L4 + c;
        uint4 p0 = pp[0];
        uint4 p1 = pp[1];
        t[0] = 2.f*t[0] - lo2f(p0.x); t[1] = 2.f*t[1] - hi2f(p0.x);
        t[2] = 2.f*t[2] - lo2f(p0.y); t[3] = 2.f*t[3] - hi2f(p0.y);
        t[4] = 2.f*t[4] - lo2f(p0.z); t[5] = 2.f*t[5] - hi2f(p0.z);
        t[6] = 2.f*t[6] - lo2f(p0.w); t[7] = 2.f*t[7] - hi2f(p0.w);
        t[8]  = 2.f*t[8]  - lo2f(p1.x); t[9]  = 2.f*t[9]  - hi2f(p1.x);
        t[10] = 2.f*t[10] - lo2f(p1.y); t[11] = 2.f*t[11] - hi2f(p1.y);
        t[12] = 2.f*t[12] - lo2f(p1.z); t[13] = 2.f*t[13] - hi2f(p1.z);
        t[14] = 2.f*t[14] - lo2f(p1.w); t[15] = 2.f*t[15] - hi2f(p1.w);
    }
    uint4 r0, r1;
    r0.x = pk2(t[0], t[1]);  r0.y = pk2(t[2], t[3]);
    r0.z = pk2(t[4], t[5]);  r0.w = pk2(t[6], t[7]);
    r1.x = pk2(t[8], t[9]);  r1.y = pk2(t[10], t[11]);
    r1.z = pk2(t[12], t[13]); r1.w = pk2(t[14], t[15]);
    uint4* q = zn + (size_t)v * L4 + c;
    q[0] = r0;
    q[1] = r1;
}

// ---- MFMA GEMM: 32-row tiles (32KB LDS, grid V/32) for TLP; A via global_load_lds
// (XOR-swizzled), B fragments hoisted to VGPRs; inner loop = ds_read_b128 + MFMA only.
template<int F, int NKK, bool DUAL, bool INIT, bool FINAL>
__global__ __launch_bounds__(256) void mfma_gemm(
    const unsigned short* __restrict__ T,
    const unsigned short* __restrict__ WtA, const unsigned short* __restrict__ WtB,
    const float* __restrict__ biasA, const float* __restrict__ biasB,
    unsigned short* __restrict__ ACC, float* __restrict__ resOut,
    float* __restrict__ part)
{
    constexpr int RPB = 32;                    // rows per block
    constexpr int CPR = F / 4;                 // 16B chunks per row (row = 2F elems)
    constexpr int FH = F / 32;
    constexpr int MT = RPB / 16;               // m-subtiles per wave
    __shared__ unsigned short tile[NKK * RPB * 2 * F];   // 32 KB

    int wv = threadIdx.x >> 6, lane = threadIdx.x & 63;
    int quad = lane >> 4, l15 = lane & 15;
    int v0 = blockIdx.x * RPB;
    int ot = wv;                                // this wave's N-subtile

    // 1) async A-tile staging: LDS slot s holds global chunk (s&~7)|((s&7)^(row&7))
    #pragma unroll
    for (int i = 0; i < 8; ++i) {
        int s = (i * 4 + wv) * 64 + lane;       // 16B-chunk id 0..2047
        int kk = s / (RPB * CPR);
        int ws = s - kk * RPB * CPR;
        int row = ws / CPR;
        int cl = ws - row * CPR;
        int cg = (cl & ~7) | ((cl & 7) ^ (row & 7));
        const unsigned short* gp = T + ((size_t)kk * V + v0 + row) * (2 * F) + cg * 8;
        gload_lds16(gp, tile + (size_t)(i * 4 + wv) * 64 * 8);
    }

    // 2) hoist this wave's B fragments while the DMA is in flight
    bf16x8 bw[NKK][FH];
    bf16x8 bd[NKK][FH];
    #pragma unroll
    for (int kk = 0; kk < NKK; ++kk) {
        #pragma unroll
        for (int fh = 0; fh < FH; ++fh) {
            size_t brow = ((size_t)kk * 64 + ot * 16 + l15) * F + fh * 32 + quad * 8;
            bw[kk][fh] = *(const bf16x8*)(const void*)(WtA + brow);
            if constexpr (DUAL) bd[kk][fh] = *(const bf16x8*)(const void*)(WtB + brow);
        }
    }

    f32x4 acc[MT][2];    // [m][batch]
    f32x4 accd[MT][2];
    #pragma unroll
    for (int m = 0; m < MT; ++m)
        #pragma unroll
        for (int b = 0; b < 2; ++b) {
            acc[m][b] = (f32x4){0.f, 0.f, 0.f, 0.f};
            if constexpr (DUAL) accd[m][b] = (f32x4){0.f, 0.f, 0.f, 0.f};
        }

    __syncthreads();    // drains staging DMA + B loads

    // 3) main loop: LDS reads + MFMA only
    #pragma unroll
    for (int kk = 0; kk < NKK; ++kk) {
        #pragma unroll
        for (int fh = 0; fh < FH; ++fh) {
            #pragma unroll
            for (int m = 0; m < MT; ++m) {
                int r = m * 16 + l15;
                int rx = r & 7;
                const unsigned short* rbase = tile + ((size_t)kk * RPB + r) * 2 * F;
                #pragma unroll
                for (int b = 0; b < 2; ++b) {
                    int c0 = b * (CPR / 2) + fh * 4 + quad;
                    int s0 = (c0 & ~7) | ((c0 & 7) ^ rx);
                    bf16x8 a = *(const bf16x8*)(const void*)(rbase + s0 * 8);
                    acc[m][b] = __builtin_amdgcn_mfma_f32_16x16x32_bf16(a, bw[kk][fh], acc[m][b], 0, 0, 0);
                    if constexpr (DUAL)
                        accd[m][b] = __builtin_amdgcn_mfma_f32_16x16x32_bf16(a, bd[kk][fh], accd[m][b], 0, 0, 0);
                }
            }
        }
    }

    // GN partial scratch reuses the consumed tile
    float* sS = (float*)tile;        // [2][64]
    float* sQ = sS + 128;
    if constexpr (FINAL) {
        __syncthreads();
    }

    // 4) epilogue: C/D layout col=l15 (-> o), row=quad*4+reg (-> v)
    int o = ot * 16 + l15;
    #pragma unroll
    for (int b = 0; b < 2; ++b) {
        float bia = FINAL ? biasA[o] : 0.f;
        float s = 0.f, q = 0.f;
        #pragma unroll
        for (int m = 0; m < MT; ++m) {
            #pragma unroll
            for (int rr = 0; rr < 4; ++rr) {
                int v = v0 + m * 16 + quad * 4 + rr;
                size_t idx = ((size_t)b * V + v) * 64 + o;
                float val = acc[m][b][rr] + bia;
                if constexpr (!INIT) val += us2f(ACC[idx]);
                ACC[idx] = f2us(val);
                if constexpr (FINAL) { s += val; q += val * val; }
                if constexpr (DUAL) resOut[idx] = accd[m][b][rr] + biasB[o];
            }
        }
        if constexpr (FINAL) {
            s += __shfl_xor(s, 16); s += __shfl_xor(s, 32);
            q += __shfl_xor(q, 16); q += __shfl_xor(q, 32);
            if (quad == 0) { sS[b * 64 + o] = s; sQ[b * 64 + o] = q; }   // exclusive slot
        }
    }
    if constexpr (FINAL) {
        __syncthreads();
        if (threadIdx.x < 128) {
            int b = threadIdx.x >> 6, oo = threadIdx.x & 63;
            atomicAdd(&part[(b * 64 + oo) * 2], sS[b * 64 + oo]);
            atomicAdd(&part[(b * 64 + oo) * 2 + 1], sQ[b * 64 + oo]);
        }
    }
}

// ---- GN finalize: per-channel partials [2][64][2] -> per-(b,g) stats [16][2] ----
__global__ __launch_bounds__(64) void gn_finalize(const float* __restrict__ part, float* __restrict__ stats) {
    int t = threadIdx.x;
    if (t < 16) {
        int b = t >> 3, g = t & 7;
        float s = 0.f, q = 0.f;
        for (int c = g * 8; c < g * 8 + 8; ++c) {
            s += part[(b * 64 + c) * 2];
            q += part[(b * 64 + c) * 2 + 1];
        }
        const float N = (float)V * 8.f;
        float mean = s / N;
        float var = q / N - mean * mean;
        stats[t * 2] = mean;
        stats[t * 2 + 1] = rsqrtf(var + EPSV);
    }
}

// ---- GN1 + LeakyReLU: ACC bf16 -> conv2 T0 [V][b*64+o] bf16 packed ----
__global__ __launch_bounds__(256) void gn_apply(const unsigned short* __restrict__ ACC,
                                                const float* __restrict__ stats,
                                                const float* __restrict__ gamma, const float* __restrict__ beta,
                                                unsigned* __restrict__ zout) {
    int idx = blockIdx.x * 256 + threadIdx.x;   // < V*64 dwords of [V][128]
    int v = idx >> 6, j2 = idx & 63;
    int b = j2 >> 5, o0 = (j2 & 31) * 2;
    float y[2];
    #pragma unroll
    for (int i = 0; i < 2; ++i) {
        int o = o0 + i;
        int bg = b * 8 + (o >> 3);
        float mean = stats[bg * 2], rstd = stats[bg * 2 + 1];
        float val = us2f(ACC[((size_t)b * V + v) * 64 + o]);
        float t = (val - mean) * rstd * gamma[o] + beta[o];
        y[i] = t > 0.f ? t : SLOPE * t;
    }
    zout[idx] = pk2(y[0], y[1]);
}

// ---- final: out[b][v][o] (holds res) += LeakyReLU(GN2(ACC)) ----
__global__ __launch_bounds__(256) void final_out(const unsigned short* __restrict__ ACC,
                                                 float* outres,
                                                 const float* __restrict__ stats,
                                                 const float* __restrict__ gamma, const float* __restrict__ beta) {
    int idx = blockIdx.x * 256 + threadIdx.x;   // < 2*V*64
    int o = idx & 63;
    int b = idx >= V * 64 ? 1 : 0;
    int bg = b * 8 + (o >> 3);
    float mean = stats[bg * 2], rstd = stats[bg * 2 + 1];
    float y = (us2f(ACC[idx]) - mean) * rstd * gamma[o] + beta[o];
    y = y > 0.f ? y : SLOPE * y;
    outres[idx] = y + outres[idx];
}

extern "C" void kernel_launch(void* const* d_in, const int* in_sizes, int n_in,
                              void* d_out, int out_size, void* d_ws, size_t ws_size,
                              hipStream_t stream) {
    const float* x    = (const float*)d_in[0];
    const float* vals = (const float*)d_in[1];
    const int*   col  = (const int*)d_in[3];
    const float* W1   = (const float*)d_in[4];
    const float* b1   = (const float*)d_in[5];
    const float* g1   = (const float*)d_in[6];
    const float* be1  = (const float*)d_in[7];
    const float* W2   = (const float*)d_in[8];
    const float* b2   = (const float*)d_in[9];
    const float* g2   = (const float*)d_in[10];
    const float* be2  = (const float*)d_in[11];
    const float* Wr   = (const float*)d_in[12];
    const float* br   = (const float*)d_in[13];
    float* out = (float*)d_out;

    // workspace (~63.1 MB): TS bf16 4*[V][128] | ACC bf16 [2][V][64] | Wt1/Wtr/Wt2 | PART/ST
    unsigned short* TS  = (unsigned short*)d_ws;
    unsigned short* ACC = TS + (size_t)4 * V * 128;
    unsigned short* Wt1 = ACC + (size_t)2 * V * 64;
    unsigned short* Wtr = Wt1 + 8 * 64 * 32;
    unsigned short* Wt2 = Wtr + 8 * 64 * 32;
    float* PART1 = (float*)(Wt2 + 8 * 64 * 64);
    float* PART2 = PART1 + 256;
    float* ST1   = PART2 + 256;
    float* ST2   = ST1 + 32;

    prep_k<<<260, 256, 0, stream>>>(W1, Wr, W2, Wt1, Wtr, Wt2, PART1);

    // ---- conv1 basis: T0..T7 in 8 slots of [V][64] bf16 ----
    uint4* T1s[8];
    for (int k = 0; k < 8; ++k) T1s[k] = (uint4*)(TS + (size_t)k * V * 64);

    reorder_k<<<V * 32 / 256, 256, 0, stream>>>(x, (unsigned*)T1s[0]);
    spmm_step<4, true><<<V * 4 / 256, 256, 0, stream>>>(T1s[0], nullptr, T1s[1], vals, col);
    for (int k = 2; k < 8; ++k)
        spmm_step<4, false><<<V * 4 / 256, 256, 0, stream>>>(T1s[k-1], T1s[k-2], T1s[k], vals, col);

    // conv1 + res: one MFMA pass over all 8 T_k (32-row tiles)
    mfma_gemm<32, 8, true, true, true><<<V / 32, 256, 0, stream>>>(
        TS, Wt1, Wtr, b1, br, ACC, out, PART1);
    gn_finalize<<<1, 64, 0, stream>>>(PART1, ST1);

    // ---- conv2: GN1-applied h1 as T0 in slot0 of [V][128] ----
    uint4* T2s[4];
    for (int k = 0; k < 4; ++k) T2s[k] = (uint4*)(TS + (size_t)k * V * 128);

    gn_apply<<<V * 64 / 256, 256, 0, stream>>>(ACC, ST1, g1, be1, (unsigned*)T2s[0]);
    spmm_step<8, true><<<V * 8 / 256, 256, 0, stream>>>(T2s[0], nullptr, T2s[1], vals, col);
    spmm_step<8, false><<<V * 8 / 256, 256, 0, stream>>>(T2s[1], T2s[0], T2s[2], vals, col);
    spmm_step<8, false><<<V * 8 / 256, 256, 0, stream>>>(T2s[2], T2s[1], T2s[3], vals, col);

    // GEMM pass a: kk 0..3 (INIT)
    mfma_gemm<64, 4, false, true, false><<<V / 32, 256, 0, stream>>>(
        TS, Wt2, nullptr, b2, nullptr, ACC, nullptr, PART2);

    // steps 4..7 reuse slots 0..3
    spmm_step<8, false><<<V * 8 / 256, 256, 0, stream>>>(T2s[3], T2s[2], T2s[0], vals, col);
    spmm_step<8, false><<<V * 8 / 256, 256, 0, stream>>>(T2s[0], T2s[3], T2s[1], vals, col);
    spmm_step<8, false><<<V * 8 / 256, 256, 0, stream>>>(T2s[1], T2s[0], T2s[2], vals, col);
    spmm_step<8, false><<<V * 8 / 256, 256, 0, stream>>>(T2s[2], T2s[1], T2s[3], vals, col);

    // GEMM pass b: kk 4..7 (RMW + bias + GN2 partials)
    mfma_gemm<64, 4, false, false, true><<<V / 32, 256, 0, stream>>>(
        TS, Wt2 + 4 * 64 * 64, nullptr, b2, nullptr, ACC, nullptr, PART2);
    gn_finalize<<<1, 64, 0, stream>>>(PART2, ST2);

    final_out<<<2 * V * 64 / 256, 256, 0, stream>>>(ACC, out, ST2, g2, be2);
}

// Round 10
// 387.108 us; speedup vs baseline: 1.2561x; 1.2561x over previous
//
#include <hip/hip_runtime.h>
#include <hip/hip_bf16.h>

#define V 49152
#define NNZ 9
#define EPSV 1e-5f
#define SLOPE 0.1f

typedef __attribute__((ext_vector_type(8))) short bf16x8;   // 8 bf16 (4 VGPRs)
typedef __attribute__((ext_vector_type(4))) float f32x4;    // MFMA C/D

__device__ __forceinline__ float lo2f(unsigned u) { return __uint_as_float(u << 16); }
__device__ __forceinline__ float hi2f(unsigned u) { return __uint_as_float(u & 0xffff0000u); }
__device__ __forceinline__ unsigned short f2us(float f) {
    __hip_bfloat16 h = __float2bfloat16(f);
    return *(unsigned short*)&h;
}
__device__ __forceinline__ float us2f(unsigned short u) { return __uint_as_float(((unsigned)u) << 16); }
__device__ __forceinline__ unsigned pk2(float a, float b) {
    return ((unsigned)f2us(a)) | (((unsigned)f2us(b)) << 16);
}

// async 16B/lane global->LDS; LDS base wave-uniform (+lane*16 auto), global addr per-lane
__device__ __forceinline__ void gload_lds16(const void* g, void* l) {
    __builtin_amdgcn_global_load_lds((__attribute__((address_space(1))) void*)g,
                                     (__attribute__((address_space(3))) void*)l, 16, 0, 0);
}

// ---- prep: convert+transpose weights to bf16 [kk][o][f]; zero GN partial buffers ----
__global__ __launch_bounds__(256) void prep_k(
    const float* __restrict__ W1, const float* __restrict__ Wr, const float* __restrict__ W2,
    unsigned short* __restrict__ Wt1, unsigned short* __restrict__ Wtr, unsigned short* __restrict__ Wt2,
    float* __restrict__ part)
{
    int i = blockIdx.x * 256 + threadIdx.x;
    if (i < 32768) {                 // Wt2[kk][o][f] = W2[kk][f][o], F=64
        int kk = i >> 12, rem = i & 4095, o = rem >> 6, f = rem & 63;
        Wt2[i] = f2us(W2[kk * 4096 + f * 64 + o]);
    } else if (i < 49152) {          // Wt1, F=32
        int j = i - 32768;
        int kk = j >> 11, rem = j & 2047, o = rem >> 5, f = rem & 31;
        Wt1[j] = f2us(W1[kk * 2048 + f * 64 + o]);
    } else if (i < 65536) {          // Wtr, F=32
        int j = i - 49152;
        int kk = j >> 11, rem = j & 2047, o = rem >> 5, f = rem & 31;
        Wtr[j] = f2us(Wr[kk * 2048 + f * 64 + o]);
    } else if (i < 66560) {
        part[i - 65536] = 0.f;
    }
}

// ---- reorder x [B,V,32] f32 -> T0 conv1 layout [V][b*32+f] bf16 (packed dwords) ----
__global__ __launch_bounds__(256) void reorder_k(const float* __restrict__ x, unsigned* __restrict__ t0) {
    int idx = blockIdx.x * 256 + threadIdx.x;   // < V*32 dwords
    int v = idx >> 5, j2 = idx & 31;
    int b = j2 >> 4, f0 = (j2 & 15) * 2;
    const float* p = x + ((size_t)b * V + v) * 32 + f0;
    t0[idx] = pk2(p[0], p[1]);
}

// ---- SpMM Chebyshev step: zn = 2*(L@zc) - zp (bf16 rows). 32B (2 uint4) per thread. ----
template<int THR, bool FIRST>
__global__ __launch_bounds__(256) void spmm_step(
    const uint4* __restrict__ zc, const uint4* __restrict__ zp, uint4* __restrict__ zn,
    const float* __restrict__ vals, const int* __restrict__ col)
{
    constexpr int L4 = THR * 2;                   // uint4 per row
    int tid = blockIdx.x * 256 + threadIdx.x;     // over V*THR
    int v = tid / THR;
    int c = (tid - v * THR) * 2;
    int base = v * NNZ;
    float t[16];
    #pragma unroll
    for (int i = 0; i < 16; ++i) t[i] = 0.f;
    #pragma unroll
    for (int n = 0; n < NNZ; ++n) {
        float a = vals[base + n];
        int cc = col[base + n];
        const uint4* p = zc + (size_t)cc * L4 + c;
        uint4 u0 = p[0];
        uint4 u1 = p[1];
        t[0] += a * lo2f(u0.x); t[1] += a * hi2f(u0.x);
        t[2] += a * lo2f(u0.y); t[3] += a * hi2f(u0.y);
        t[4] += a * lo2f(u0.z); t[5] += a * hi2f(u0.z);
        t[6] += a * lo2f(u0.w); t[7] += a * hi2f(u0.w);
        t[8]  += a * lo2f(u1.x); t[9]  += a * hi2f(u1.x);
        t[10] += a * lo2f(u1.y); t[11] += a * hi2f(u1.y);
        t[12] += a * lo2f(u1.z); t[13] += a * hi2f(u1.z);
        t[14] += a * lo2f(u1.w); t[15] += a * hi2f(u1.w);
    }
    if (!FIRST) {
        const uint4* pp = zp + (size_t)v * L4 + c;
        uint4 p0 = pp[0];
        uint4 p1 = pp[1];
        t[0] = 2.f*t[0] - lo2f(p0.x); t[1] = 2.f*t[1] - hi2f(p0.x);
        t[2] = 2.f*t[2] - lo2f(p0.y); t[3] = 2.f*t[3] - hi2f(p0.y);
        t[4] = 2.f*t[4] - lo2f(p0.z); t[5] = 2.f*t[5] - hi2f(p0.z);
        t[6] = 2.f*t[6] - lo2f(p0.w); t[7] = 2.f*t[7] - hi2f(p0.w);
        t[8]  = 2.f*t[8]  - lo2f(p1.x); t[9]  = 2.f*t[9]  - hi2f(p1.x);
        t[10] = 2.f*t[10] - lo2f(p1.y); t[11] = 2.f*t[11] - hi2f(p1.y);
        t[12] = 2.f*t[12] - lo2f(p1.z); t[13] = 2.f*t[13] - hi2f(p1.z);
        t[14] = 2.f*t[14] - lo2f(p1.w); t[15] = 2.f*t[15] - hi2f(p1.w);
    }
    uint4 r0, r1;
    r0.x = pk2(t[0], t[1]);  r0.y = pk2(t[2], t[3]);
    r0.z = pk2(t[4], t[5]);  r0.w = pk2(t[6], t[7]);
    r1.x = pk2(t[8], t[9]);  r1.y = pk2(t[10], t[11]);
    r1.z = pk2(t[12], t[13]); r1.w = pk2(t[14], t[15]);
    uint4* q = zn + (size_t)v * L4 + c;
    q[0] = r0;
    q[1] = r1;
}

// ---- MFMA GEMM: 64-row tile (R8 config) + LDS-transposed, fully coalesced epilogue.
// A via global_load_lds (XOR-swizzled), B fragments hoisted to VGPRs,
// inner loop = ds_read_b128 + MFMA only. Epilogue: regs -> LDS [b][r][o] -> uint4/float4
// streaming stores (no write-allocate round trips). GN partials per-group in store phase.
template<int F, int NKK, bool DUAL, bool INIT, bool FINAL>
__global__ __launch_bounds__(256) void mfma_gemm(
    const unsigned short* __restrict__ T,
    const unsigned short* __restrict__ WtA, const unsigned short* __restrict__ WtB,
    const float* __restrict__ biasA, const float* __restrict__ biasB,
    unsigned short* __restrict__ ACC, float* __restrict__ resOut,
    float* __restrict__ part)
{
    constexpr int CPR = F / 4;                 // 16B chunks per row (row = 2F bf16)
    constexpr int FH = F / 32;
    constexpr int RST = 68;                    // transpose row stride (floats)
    constexpr int STAGE_SH = NKK * 64 * 2 * F; // shorts (64KB)
    constexpr int TRANS_SH = (DUAL ? 2 : 1) * 2 * 64 * RST * 2;  // shorts equiv of floats
    constexpr int SH = STAGE_SH > TRANS_SH ? STAGE_SH : TRANS_SH;
    __shared__ unsigned short shraw[SH];
    __shared__ float sGrp[32];                 // [0:16) sum, [16:32) sumsq per (b*8+g)

    unsigned short* tile = shraw;
    float* accbuf  = (float*)shraw;                       // [2][64][RST]
    float* dualbuf = accbuf + 2 * 64 * RST;

    int wv = threadIdx.x >> 6, lane = threadIdx.x & 63;
    int quad = lane >> 4, l15 = lane & 15;
    int v0 = blockIdx.x * 64;
    int ot = wv;                                // this wave's N-subtile

    // 1) async A-tile staging: LDS slot s holds global chunk (s&~7)|((s&7)^(row&7))
    #pragma unroll
    for (int i = 0; i < 16; ++i) {
        int s = (i * 4 + wv) * 64 + lane;       // 16B-chunk id 0..4095
        int kk = s / (64 * CPR);
        int ws = s - kk * 64 * CPR;
        int row = ws / CPR;
        int cl = ws - row * CPR;
        int cg = (cl & ~7) | ((cl & 7) ^ (row & 7));
        const unsigned short* gp = T + ((size_t)kk * V + v0 + row) * (2 * F) + cg * 8;
        gload_lds16(gp, tile + (size_t)(i * 4 + wv) * 64 * 8);
    }

    // 2) hoist this wave's B fragments while the DMA is in flight
    bf16x8 bw[NKK][FH];
    bf16x8 bd[NKK][FH];
    #pragma unroll
    for (int kk = 0; kk < NKK; ++kk) {
        #pragma unroll
        for (int fh = 0; fh < FH; ++fh) {
            size_t brow = ((size_t)kk * 64 + ot * 16 + l15) * F + fh * 32 + quad * 8;
            bw[kk][fh] = *(const bf16x8*)(const void*)(WtA + brow);
            if constexpr (DUAL) bd[kk][fh] = *(const bf16x8*)(const void*)(WtB + brow);
        }
    }

    f32x4 acc[4][2];    // [m][batch]
    f32x4 accd[4][2];
    #pragma unroll
    for (int m = 0; m < 4; ++m)
        #pragma unroll
        for (int b = 0; b < 2; ++b) {
            acc[m][b] = (f32x4){0.f, 0.f, 0.f, 0.f};
            if constexpr (DUAL) accd[m][b] = (f32x4){0.f, 0.f, 0.f, 0.f};
        }

    __syncthreads();    // drains staging DMA + B loads

    // 3) main loop: LDS reads + MFMA only
    #pragma unroll
    for (int kk = 0; kk < NKK; ++kk) {
        #pragma unroll
        for (int fh = 0; fh < FH; ++fh) {
            #pragma unroll
            for (int m = 0; m < 4; ++m) {
                int r = m * 16 + l15;
                int rx = r & 7;
                const unsigned short* rbase = tile + ((size_t)kk * 64 + r) * 2 * F;
                #pragma unroll
                for (int b = 0; b < 2; ++b) {
                    int c0 = b * (CPR / 2) + fh * 4 + quad;
                    int s0 = (c0 & ~7) | ((c0 & 7) ^ rx);
                    bf16x8 a = *(const bf16x8*)(const void*)(rbase + s0 * 8);
                    acc[m][b] = __builtin_amdgcn_mfma_f32_16x16x32_bf16(a, bw[kk][fh], acc[m][b], 0, 0, 0);
                    if constexpr (DUAL)
                        accd[m][b] = __builtin_amdgcn_mfma_f32_16x16x32_bf16(a, bd[kk][fh], accd[m][b], 0, 0, 0);
                }
            }
        }
    }

    // 4) epilogue: transpose through LDS, then coalesced streaming stores
    __syncthreads();    // tile fully consumed before reuse

    int o = ot * 16 + l15;
    float bia = FINAL ? biasA[o] : 0.f;
    float biaB = DUAL ? biasB[o] : 0.f;
    #pragma unroll
    for (int m = 0; m < 4; ++m) {
        #pragma unroll
        for (int b = 0; b < 2; ++b) {
            #pragma unroll
            for (int rr = 0; rr < 4; ++rr) {
                int r = m * 16 + quad * 4 + rr;
                accbuf[(b * 64 + r) * RST + o] = acc[m][b][rr] + bia;
                if constexpr (DUAL) dualbuf[(b * 64 + r) * RST + o] = accd[m][b][rr] + biaB;
            }
        }
    }
    if constexpr (FINAL) {
        if (threadIdx.x < 32) sGrp[threadIdx.x] = 0.f;
    }
    __syncthreads();

    // ACC: 1024 uint4 chunks (8 bf16 = one GN group-octet each), coalesced
    #pragma unroll
    for (int j = 0; j < 4; ++j) {
        int cid = threadIdx.x + 256 * j;        // 0..1023
        int g = cid & 7, r = (cid >> 3) & 63, b = cid >> 9;
        int o0 = g * 8;
        const float* src = accbuf + (b * 64 + r) * RST + o0;
        float e[8];
        #pragma unroll
        for (int i = 0; i < 8; ++i) e[i] = src[i];
        size_t gidx = ((size_t)b * V + v0 + r) * 64 + o0;
        if constexpr (!INIT) {
            uint4 old = *(const uint4*)(const void*)(ACC + gidx);
            e[0] += lo2f(old.x); e[1] += hi2f(old.x);
            e[2] += lo2f(old.y); e[3] += hi2f(old.y);
            e[4] += lo2f(old.z); e[5] += hi2f(old.z);
            e[6] += lo2f(old.w); e[7] += hi2f(old.w);
        }
        uint4 pk;
        pk.x = pk2(e[0], e[1]); pk.y = pk2(e[2], e[3]);
        pk.z = pk2(e[4], e[5]); pk.w = pk2(e[6], e[7]);
        *(uint4*)(void*)(ACC + gidx) = pk;
        if constexpr (FINAL) {
            float s = 0.f, q = 0.f;
            #pragma unroll
            for (int i = 0; i < 8; ++i) { s += e[i]; q += e[i] * e[i]; }
            atomicAdd(&sGrp[b * 8 + g], s);
            atomicAdd(&sGrp[16 + b * 8 + g], q);
        }
    }
    if constexpr (DUAL) {
        // res: 2048 float4 chunks, coalesced
        #pragma unroll
        for (int j = 0; j < 8; ++j) {
            int cid = threadIdx.x + 256 * j;    // 0..2047
            int oc = cid & 15, r = (cid >> 4) & 63, b = cid >> 10;
            float4 vv = *(const float4*)(const void*)(dualbuf + (b * 64 + r) * RST + oc * 4);
            *(float4*)(void*)(resOut + ((size_t)b * V + v0 + r) * 64 + oc * 4) = vv;
        }
    }
    if constexpr (FINAL) {
        __syncthreads();
        if (threadIdx.x < 16) {
            atomicAdd(&part[threadIdx.x * 2],     sGrp[threadIdx.x]);
            atomicAdd(&part[threadIdx.x * 2 + 1], sGrp[16 + threadIdx.x]);
        }
    }
}

// ---- GN finalize: per-group sums part[16][2] -> stats [16][2] (mean, rstd) ----
__global__ __launch_bounds__(64) void gn_finalize(const float* __restrict__ part, float* __restrict__ stats) {
    int t = threadIdx.x;
    if (t < 16) {
        const float N = (float)V * 8.f;
        float mean = part[t * 2] / N;
        float var = part[t * 2 + 1] / N - mean * mean;
        stats[t * 2] = mean;
        stats[t * 2 + 1] = rsqrtf(var + EPSV);
    }
}

// ---- GN1 + LeakyReLU: ACC bf16 -> conv2 T0 [V][b*64+o] bf16 packed ----
__global__ __launch_bounds__(256) void gn_apply(const unsigned short* __restrict__ ACC,
                                                const float* __restrict__ stats,
                                                const float* __restrict__ gamma, const float* __restrict__ beta,
                                                unsigned* __restrict__ zout) {
    int idx = blockIdx.x * 256 + threadIdx.x;   // < V*64 dwords of [V][128]
    int v = idx >> 6, j2 = idx & 63;
    int b = j2 >> 5, o0 = (j2 & 31) * 2;
    float y[2];
    #pragma unroll
    for (int i = 0; i < 2; ++i) {
        int o = o0 + i;
        int bg = b * 8 + (o >> 3);
        float mean = stats[bg * 2], rstd = stats[bg * 2 + 1];
        float val = us2f(ACC[((size_t)b * V + v) * 64 + o]);
        float t = (val - mean) * rstd * gamma[o] + beta[o];
        y[i] = t > 0.f ? t : SLOPE * t;
    }
    zout[idx] = pk2(y[0], y[1]);
}

// ---- final: out[b][v][o] (holds res) += LeakyReLU(GN2(ACC)) ----
__global__ __launch_bounds__(256) void final_out(const unsigned short* __restrict__ ACC,
                                                 float* outres,
                                                 const float* __restrict__ stats,
                                                 const float* __restrict__ gamma, const float* __restrict__ beta) {
    int idx = blockIdx.x * 256 + threadIdx.x;   // < 2*V*64
    int o = idx & 63;
    int b = idx >= V * 64 ? 1 : 0;
    int bg = b * 8 + (o >> 3);
    float mean = stats[bg * 2], rstd = stats[bg * 2 + 1];
    float y = (us2f(ACC[idx]) - mean) * rstd * gamma[o] + beta[o];
    y = y > 0.f ? y : SLOPE * y;
    outres[idx] = y + outres[idx];
}

extern "C" void kernel_launch(void* const* d_in, const int* in_sizes, int n_in,
                              void* d_out, int out_size, void* d_ws, size_t ws_size,
                              hipStream_t stream) {
    const float* x    = (const float*)d_in[0];
    const float* vals = (const float*)d_in[1];
    const int*   col  = (const int*)d_in[3];
    const float* W1   = (const float*)d_in[4];
    const float* b1   = (const float*)d_in[5];
    const float* g1   = (const float*)d_in[6];
    const float* be1  = (const float*)d_in[7];
    const float* W2   = (const float*)d_in[8];
    const float* b2   = (const float*)d_in[9];
    const float* g2   = (const float*)d_in[10];
    const float* be2  = (const float*)d_in[11];
    const float* Wr   = (const float*)d_in[12];
    const float* br   = (const float*)d_in[13];
    float* out = (float*)d_out;

    // workspace (~63.1 MB): TS bf16 4*[V][128] | ACC bf16 [2][V][64] | Wt1/Wtr/Wt2 | PART/ST
    unsigned short* TS  = (unsigned short*)d_ws;
    unsigned short* ACC = TS + (size_t)4 * V * 128;
    unsigned short* Wt1 = ACC + (size_t)2 * V * 64;
    unsigned short* Wtr = Wt1 + 8 * 64 * 32;
    unsigned short* Wt2 = Wtr + 8 * 64 * 32;
    float* PART1 = (float*)(Wt2 + 8 * 64 * 64);
    float* PART2 = PART1 + 32;
    float* ST1   = PART2 + 32;
    float* ST2   = ST1 + 32;

    prep_k<<<260, 256, 0, stream>>>(W1, Wr, W2, Wt1, Wtr, Wt2, PART1);

    // ---- conv1 basis: T0..T7 in 8 slots of [V][64] bf16 ----
    uint4* T1s[8];
    for (int k = 0; k < 8; ++k) T1s[k] = (uint4*)(TS + (size_t)k * V * 64);

    reorder_k<<<V * 32 / 256, 256, 0, stream>>>(x, (unsigned*)T1s[0]);
    spmm_step<4, true><<<V * 4 / 256, 256, 0, stream>>>(T1s[0], nullptr, T1s[1], vals, col);
    for (int k = 2; k < 8; ++k)
        spmm_step<4, false><<<V * 4 / 256, 256, 0, stream>>>(T1s[k-1], T1s[k-2], T1s[k], vals, col);

    // conv1 + res: one MFMA pass over all 8 T_k (64-row tiles)
    mfma_gemm<32, 8, true, true, true><<<V / 64, 256, 0, stream>>>(
        TS, Wt1, Wtr, b1, br, ACC, out, PART1);
    gn_finalize<<<1, 64, 0, stream>>>(PART1, ST1);

    // ---- conv2: GN1-applied h1 as T0 in slot0 of [V][128] ----
    uint4* T2s[4];
    for (int k = 0; k < 4; ++k) T2s[k] = (uint4*)(TS + (size_t)k * V * 128);

    gn_apply<<<V * 64 / 256, 256, 0, stream>>>(ACC, ST1, g1, be1, (unsigned*)T2s[0]);
    spmm_step<8, true><<<V * 8 / 256, 256, 0, stream>>>(T2s[0], nullptr, T2s[1], vals, col);
    spmm_step<8, false><<<V * 8 / 256, 256, 0, stream>>>(T2s[1], T2s[0], T2s[2], vals, col);
    spmm_step<8, false><<<V * 8 / 256, 256, 0, stream>>>(T2s[2], T2s[1], T2s[3], vals, col);

    // GEMM pass a: kk 0..3 (INIT)
    mfma_gemm<64, 4, false, true, false><<<V / 64, 256, 0, stream>>>(
        TS, Wt2, nullptr, b2, nullptr, ACC, nullptr, PART2);

    // steps 4..7 reuse slots 0..3
    spmm_step<8, false><<<V * 8 / 256, 256, 0, stream>>>(T2s[3], T2s[2], T2s[0], vals, col);
    spmm_step<8, false><<<V * 8 / 256, 256, 0, stream>>>(T2s[0], T2s[3], T2s[1], vals, col);
    spmm_step<8, false><<<V * 8 / 256, 256, 0, stream>>>(T2s[1], T2s[0], T2s[2], vals, col);
    spmm_step<8, false><<<V * 8 / 256, 256, 0, stream>>>(T2s[2], T2s[1], T2s[3], vals, col);

    // GEMM pass b: kk 4..7 (RMW + bias + GN2 partials)
    mfma_gemm<64, 4, false, false, true><<<V / 64, 256, 0, stream>>>(
        TS, Wt2 + 4 * 64 * 64, nullptr, b2, nullptr, ACC, nullptr, PART2);
    gn_finalize<<<1, 64, 0, stream>>>(PART2, ST2);

    final_out<<<2 * V * 64 / 256, 256, 0, stream>>>(ACC, out, ST2, g2, be2);
}

// Round 11
// 366.539 us; speedup vs baseline: 1.3266x; 1.0561x over previous
//
#include <hip/hip_runtime.h>
#include <hip/hip_bf16.h>

#define V 49152
#define NNZ 9
#define EPSV 1e-5f
#define SLOPE 0.1f

typedef __attribute__((ext_vector_type(8))) short bf16x8;   // 8 bf16 (4 VGPRs)
typedef __attribute__((ext_vector_type(4))) float f32x4;    // MFMA C/D

__device__ __forceinline__ float lo2f(unsigned u) { return __uint_as_float(u << 16); }
__device__ __forceinline__ float hi2f(unsigned u) { return __uint_as_float(u & 0xffff0000u); }
__device__ __forceinline__ unsigned short f2us(float f) {
    __hip_bfloat16 h = __float2bfloat16(f);
    return *(unsigned short*)&h;
}
__device__ __forceinline__ float us2f(unsigned short u) { return __uint_as_float(((unsigned)u) << 16); }
__device__ __forceinline__ unsigned pk2(float a, float b) {
    return ((unsigned)f2us(a)) | (((unsigned)f2us(b)) << 16);
}

// async 16B/lane global->LDS; LDS base wave-uniform (+lane*16 auto), global addr per-lane
__device__ __forceinline__ void gload_lds16(const void* g, void* l) {
    __builtin_amdgcn_global_load_lds((__attribute__((address_space(1))) void*)g,
                                     (__attribute__((address_space(3))) void*)l, 16, 0, 0);
}

// ---- prep: convert+transpose weights to bf16 [kk][o][f]; zero GN partial buffers ----
__global__ __launch_bounds__(256) void prep_k(
    const float* __restrict__ W1, const float* __restrict__ Wr, const float* __restrict__ W2,
    unsigned short* __restrict__ Wt1, unsigned short* __restrict__ Wtr, unsigned short* __restrict__ Wt2,
    float* __restrict__ part)
{
    int i = blockIdx.x * 256 + threadIdx.x;
    if (i < 32768) {                 // Wt2[kk][o][f] = W2[kk][f][o], F=64
        int kk = i >> 12, rem = i & 4095, o = rem >> 6, f = rem & 63;
        Wt2[i] = f2us(W2[kk * 4096 + f * 64 + o]);
    } else if (i < 49152) {          // Wt1, F=32
        int j = i - 32768;
        int kk = j >> 11, rem = j & 2047, o = rem >> 5, f = rem & 31;
        Wt1[j] = f2us(W1[kk * 2048 + f * 64 + o]);
    } else if (i < 65536) {          // Wtr, F=32
        int j = i - 49152;
        int kk = j >> 11, rem = j & 2047, o = rem >> 5, f = rem & 31;
        Wtr[j] = f2us(Wr[kk * 2048 + f * 64 + o]);
    } else if (i < 66560) {
        part[i - 65536] = 0.f;
    }
}

// ---- reorder x [B,V,32] f32 -> T0 conv1 layout [V][b*32+f] bf16 (packed dwords) ----
__global__ __launch_bounds__(256) void reorder_k(const float* __restrict__ x, unsigned* __restrict__ t0) {
    int idx = blockIdx.x * 256 + threadIdx.x;   // < V*32 dwords
    int v = idx >> 5, j2 = idx & 31;
    int b = j2 >> 4, f0 = (j2 & 15) * 2;
    const float* p = x + ((size_t)b * V + v) * 32 + f0;
    t0[idx] = pk2(p[0], p[1]);
}

// ---- SpMM Chebyshev step: zn = 2*(L@zc) - zp (bf16 rows). 32B (2 uint4) per thread. ----
template<int THR, bool FIRST>
__global__ __launch_bounds__(256) void spmm_step(
    const uint4* __restrict__ zc, const uint4* __restrict__ zp, uint4* __restrict__ zn,
    const float* __restrict__ vals, const int* __restrict__ col)
{
    constexpr int L4 = THR * 2;                   // uint4 per row
    int tid = blockIdx.x * 256 + threadIdx.x;     // over V*THR
    int v = tid / THR;
    int c = (tid - v * THR) * 2;
    int base = v * NNZ;
    float t[16];
    #pragma unroll
    for (int i = 0; i < 16; ++i) t[i] = 0.f;
    #pragma unroll
    for (int n = 0; n < NNZ; ++n) {
        float a = vals[base + n];
        int cc = col[base + n];
        const uint4* p = zc + (size_t)cc * L4 + c;
        uint4 u0 = p[0];
        uint4 u1 = p[1];
        t[0] += a * lo2f(u0.x); t[1] += a * hi2f(u0.x);
        t[2] += a * lo2f(u0.y); t[3] += a * hi2f(u0.y);
        t[4] += a * lo2f(u0.z); t[5] += a * hi2f(u0.z);
        t[6] += a * lo2f(u0.w); t[7] += a * hi2f(u0.w);
        t[8]  += a * lo2f(u1.x); t[9]  += a * hi2f(u1.x);
        t[10] += a * lo2f(u1.y); t[11] += a * hi2f(u1.y);
        t[12] += a * lo2f(u1.z); t[13] += a * hi2f(u1.z);
        t[14] += a * lo2f(u1.w); t[15] += a * hi2f(u1.w);
    }
    if (!FIRST) {
        const uint4* pp = zp + (size_t)v * L4 + c;
        uint4 p0 = pp[0];
        uint4 p1 = pp[1];
        t[0] = 2.f*t[0] - lo2f(p0.x); t[1] = 2.f*t[1] - hi2f(p0.x);
        t[2] = 2.f*t[2] - lo2f(p0.y); t[3] = 2.f*t[3] - hi2f(p0.y);
        t[4] = 2.f*t[4] - lo2f(p0.z); t[5] = 2.f*t[5] - hi2f(p0.z);
        t[6] = 2.f*t[6] - lo2f(p0.w); t[7] = 2.f*t[7] - hi2f(p0.w);
        t[8]  = 2.f*t[8]  - lo2f(p1.x); t[9]  = 2.f*t[9]  - hi2f(p1.x);
        t[10] = 2.f*t[10] - lo2f(p1.y); t[11] = 2.f*t[11] - hi2f(p1.y);
        t[12] = 2.f*t[12] - lo2f(p1.z); t[13] = 2.f*t[13] - hi2f(p1.z);
        t[14] = 2.f*t[14] - lo2f(p1.w); t[15] = 2.f*t[15] - hi2f(p1.w);
    }
    uint4 r0, r1;
    r0.x = pk2(t[0], t[1]);  r0.y = pk2(t[2], t[3]);
    r0.z = pk2(t[4], t[5]);  r0.w = pk2(t[6], t[7]);
    r1.x = pk2(t[8], t[9]);  r1.y = pk2(t[10], t[11]);
    r1.z = pk2(t[12], t[13]); r1.w = pk2(t[14], t[15]);
    uint4* q = zn + (size_t)v * L4 + c;
    q[0] = r0;
    q[1] = r1;
}

// ---- MFMA GEMM: 64-row tile, NPH staging phases over NKK k-slices, B hoisted to VGPRs,
// inner loop = ds_read_b128 + MFMA, LDS-transposed coalesced epilogue + GN partials. ----
template<int F, int NKK, int NPH, bool DUAL, bool INIT, bool FINAL>
__global__ __launch_bounds__(256) void mfma_gemm(
    const unsigned short* __restrict__ T,
    const unsigned short* __restrict__ WtA, const unsigned short* __restrict__ WtB,
    const float* __restrict__ biasA, const float* __restrict__ biasB,
    unsigned short* __restrict__ ACC, float* __restrict__ resOut,
    float* __restrict__ part)
{
    constexpr int KPP = NKK / NPH;             // k-slices per staging phase
    constexpr int CPR = F / 4;                 // 16B chunks per row (row = 2F bf16)
    constexpr int FH = F / 32;
    constexpr int RST = 68;                    // transpose row stride (floats)
    constexpr int STAGE_SH = KPP * 64 * 2 * F; // shorts (64KB per phase)
    constexpr int TRANS_SH = (DUAL ? 2 : 1) * 2 * 64 * RST * 2;
    constexpr int SH = STAGE_SH > TRANS_SH ? STAGE_SH : TRANS_SH;
    __shared__ unsigned short shraw[SH];
    __shared__ float sGrp[32];

    unsigned short* tile = shraw;
    float* accbuf  = (float*)shraw;                       // [2][64][RST]
    float* dualbuf = accbuf + 2 * 64 * RST;

    int wv = threadIdx.x >> 6, lane = threadIdx.x & 63;
    int quad = lane >> 4, l15 = lane & 15;
    int v0 = blockIdx.x * 64;
    int ot = wv;                                // this wave's N-subtile

    bf16x8 bw[NKK][FH];
    bf16x8 bd[NKK][FH];
    f32x4 acc[4][2];    // [m][batch]
    f32x4 accd[4][2];

    #pragma unroll
    for (int ph = 0; ph < NPH; ++ph) {
        if (ph > 0) __syncthreads();            // prior phase's tile fully consumed

        // 1) async A staging for this phase's KPP k-slices (XOR-swizzled chunks)
        #pragma unroll
        for (int i = 0; i < (KPP * 64 * CPR) / 256; ++i) {
            int s = (i * 4 + wv) * 64 + lane;   // 16B-chunk id within phase
            int kkl = s / (64 * CPR);
            int ws = s - kkl * 64 * CPR;
            int row = ws / CPR;
            int cl = ws - row * CPR;
            int cg = (cl & ~7) | ((cl & 7) ^ (row & 7));
            const unsigned short* gp =
                T + ((size_t)(ph * KPP + kkl) * V + v0 + row) * (2 * F) + cg * 8;
            gload_lds16(gp, tile + (size_t)(i * 4 + wv) * 64 * 8);
        }

        if (ph == 0) {
            // 2) hoist ALL B fragments while the first DMA is in flight
            #pragma unroll
            for (int kk = 0; kk < NKK; ++kk) {
                #pragma unroll
                for (int fh = 0; fh < FH; ++fh) {
                    size_t brow = ((size_t)kk * 64 + ot * 16 + l15) * F + fh * 32 + quad * 8;
                    bw[kk][fh] = *(const bf16x8*)(const void*)(WtA + brow);
                    if constexpr (DUAL) bd[kk][fh] = *(const bf16x8*)(const void*)(WtB + brow);
                }
            }
            #pragma unroll
            for (int m = 0; m < 4; ++m)
                #pragma unroll
                for (int b = 0; b < 2; ++b) {
                    acc[m][b] = (f32x4){0.f, 0.f, 0.f, 0.f};
                    if constexpr (DUAL) accd[m][b] = (f32x4){0.f, 0.f, 0.f, 0.f};
                }
        }

        __syncthreads();    // drain staging DMA (+ B loads on ph 0)

        // 3) compute this phase: LDS reads + MFMA only
        #pragma unroll
        for (int kkl = 0; kkl < KPP; ++kkl) {
            int kk = ph * KPP + kkl;
            #pragma unroll
            for (int fh = 0; fh < FH; ++fh) {
                #pragma unroll
                for (int m = 0; m < 4; ++m) {
                    int r = m * 16 + l15;
                    int rx = r & 7;
                    const unsigned short* rbase = tile + ((size_t)kkl * 64 + r) * 2 * F;
                    #pragma unroll
                    for (int b = 0; b < 2; ++b) {
                        int c0 = b * (CPR / 2) + fh * 4 + quad;
                        int s0 = (c0 & ~7) | ((c0 & 7) ^ rx);
                        bf16x8 a = *(const bf16x8*)(const void*)(rbase + s0 * 8);
                        acc[m][b] = __builtin_amdgcn_mfma_f32_16x16x32_bf16(a, bw[kk][fh], acc[m][b], 0, 0, 0);
                        if constexpr (DUAL)
                            accd[m][b] = __builtin_amdgcn_mfma_f32_16x16x32_bf16(a, bd[kk][fh], accd[m][b], 0, 0, 0);
                    }
                }
            }
        }
    }

    // 4) epilogue: transpose through LDS, then coalesced streaming stores
    __syncthreads();

    int o = ot * 16 + l15;
    float bia = FINAL ? biasA[o] : 0.f;
    float biaB = DUAL ? biasB[o] : 0.f;
    #pragma unroll
    for (int m = 0; m < 4; ++m) {
        #pragma unroll
        for (int b = 0; b < 2; ++b) {
            #pragma unroll
            for (int rr = 0; rr < 4; ++rr) {
                int r = m * 16 + quad * 4 + rr;
                accbuf[(b * 64 + r) * RST + o] = acc[m][b][rr] + bia;
                if constexpr (DUAL) dualbuf[(b * 64 + r) * RST + o] = accd[m][b][rr] + biaB;
            }
        }
    }
    if constexpr (FINAL) {
        if (threadIdx.x < 32) sGrp[threadIdx.x] = 0.f;
    }
    __syncthreads();

    // ACC: 1024 uint4 chunks (8 bf16 = one GN group-octet each), coalesced
    #pragma unroll
    for (int j = 0; j < 4; ++j) {
        int cid = threadIdx.x + 256 * j;        // 0..1023
        int g = cid & 7, r = (cid >> 3) & 63, b = cid >> 9;
        int o0 = g * 8;
        const float* src = accbuf + (b * 64 + r) * RST + o0;
        float e[8];
        #pragma unroll
        for (int i = 0; i < 8; ++i) e[i] = src[i];
        size_t gidx = ((size_t)b * V + v0 + r) * 64 + o0;
        if constexpr (!INIT) {
            uint4 old = *(const uint4*)(const void*)(ACC + gidx);
            e[0] += lo2f(old.x); e[1] += hi2f(old.x);
            e[2] += lo2f(old.y); e[3] += hi2f(old.y);
            e[4] += lo2f(old.z); e[5] += hi2f(old.z);
            e[6] += lo2f(old.w); e[7] += hi2f(old.w);
        }
        uint4 pk;
        pk.x = pk2(e[0], e[1]); pk.y = pk2(e[2], e[3]);
        pk.z = pk2(e[4], e[5]); pk.w = pk2(e[6], e[7]);
        *(uint4*)(void*)(ACC + gidx) = pk;
        if constexpr (FINAL) {
            float s = 0.f, q = 0.f;
            #pragma unroll
            for (int i = 0; i < 8; ++i) { s += e[i]; q += e[i] * e[i]; }
            atomicAdd(&sGrp[b * 8 + g], s);
            atomicAdd(&sGrp[16 + b * 8 + g], q);
        }
    }
    if constexpr (DUAL) {
        // res: 2048 float4 chunks, coalesced
        #pragma unroll
        for (int j = 0; j < 8; ++j) {
            int cid = threadIdx.x + 256 * j;    // 0..2047
            int oc = cid & 15, r = (cid >> 4) & 63, b = cid >> 10;
            float4 vv = *(const float4*)(const void*)(dualbuf + (b * 64 + r) * RST + oc * 4);
            *(float4*)(void*)(resOut + ((size_t)b * V + v0 + r) * 64 + oc * 4) = vv;
        }
    }
    if constexpr (FINAL) {
        __syncthreads();
        if (threadIdx.x < 16) {
            atomicAdd(&part[threadIdx.x * 2],     sGrp[threadIdx.x]);
            atomicAdd(&part[threadIdx.x * 2 + 1], sGrp[16 + threadIdx.x]);
        }
    }
}

// ---- GN1 + LeakyReLU (stats inline from PART): ACC bf16 -> conv2 T0 [V][b*64+o] ----
__global__ __launch_bounds__(256) void gn_apply(const unsigned short* __restrict__ ACC,
                                                const float* __restrict__ part,
                                                const float* __restrict__ gamma, const float* __restrict__ beta,
                                                unsigned* __restrict__ zout) {
    int idx = blockIdx.x * 256 + threadIdx.x;   // < V*16 (8-channel chunks)
    int v = idx >> 4, j = idx & 15;             // j = b*8+g
    int b = j >> 3, g = j & 7;
    const float N = (float)V * 8.f;
    float mean = part[j * 2] / N;
    float rstd = rsqrtf(part[j * 2 + 1] / N - mean * mean + EPSV);
    int o0 = g * 8;
    uint4 aa = *(const uint4*)(const void*)(ACC + ((size_t)b * V + v) * 64 + o0);
    float e[8] = { lo2f(aa.x), hi2f(aa.x), lo2f(aa.y), hi2f(aa.y),
                   lo2f(aa.z), hi2f(aa.z), lo2f(aa.w), hi2f(aa.w) };
    float y[8];
    #pragma unroll
    for (int i = 0; i < 8; ++i) {
        float t = (e[i] - mean) * rstd * gamma[o0 + i] + beta[o0 + i];
        y[i] = t > 0.f ? t : SLOPE * t;
    }
    uint4 pk;
    pk.x = pk2(y[0], y[1]); pk.y = pk2(y[2], y[3]);
    pk.z = pk2(y[4], y[5]); pk.w = pk2(y[6], y[7]);
    *(uint4*)(void*)(zout + (size_t)v * 64 + b * 32 + g * 4) = pk;
}

// ---- final (stats inline): out[b][v][o] (holds res) += LeakyReLU(GN2(ACC)) ----
__global__ __launch_bounds__(256) void final_out(const unsigned short* __restrict__ ACC,
                                                 float* outres,
                                                 const float* __restrict__ part,
                                                 const float* __restrict__ gamma, const float* __restrict__ beta) {
    int idx = blockIdx.x * 256 + threadIdx.x;   // < 2*V*8 (8-channel chunks)
    int b = idx >= V * 8 ? 1 : 0;
    int r = idx - b * V * 8;
    int v = r >> 3, g = r & 7;
    int j = b * 8 + g;
    const float N = (float)V * 8.f;
    float mean = part[j * 2] / N;
    float rstd = rsqrtf(part[j * 2 + 1] / N - mean * mean + EPSV);
    int o0 = g * 8;
    size_t base = ((size_t)b * V + v) * 64 + o0;
    uint4 aa = *(const uint4*)(const void*)(ACC + base);
    float e[8] = { lo2f(aa.x), hi2f(aa.x), lo2f(aa.y), hi2f(aa.y),
                   lo2f(aa.z), hi2f(aa.z), lo2f(aa.w), hi2f(aa.w) };
    float4 r0 = *(const float4*)(const void*)(outres + base);
    float4 r1 = *(const float4*)(const void*)(outres + base + 4);
    float y[8];
    #pragma unroll
    for (int i = 0; i < 8; ++i) {
        float t = (e[i] - mean) * rstd * gamma[o0 + i] + beta[o0 + i];
        y[i] = t > 0.f ? t : SLOPE * t;
    }
    float4 w0 = { y[0] + r0.x, y[1] + r0.y, y[2] + r0.z, y[3] + r0.w };
    float4 w1 = { y[4] + r1.x, y[5] + r1.y, y[6] + r1.z, y[7] + r1.w };
    *(float4*)(void*)(outres + base) = w0;
    *(float4*)(void*)(outres + base + 4) = w1;
}

extern "C" void kernel_launch(void* const* d_in, const int* in_sizes, int n_in,
                              void* d_out, int out_size, void* d_ws, size_t ws_size,
                              hipStream_t stream) {
    const float* x    = (const float*)d_in[0];
    const float* vals = (const float*)d_in[1];
    const int*   col  = (const int*)d_in[3];
    const float* W1   = (const float*)d_in[4];
    const float* b1   = (const float*)d_in[5];
    const float* g1   = (const float*)d_in[6];
    const float* be1  = (const float*)d_in[7];
    const float* W2   = (const float*)d_in[8];
    const float* b2   = (const float*)d_in[9];
    const float* g2   = (const float*)d_in[10];
    const float* be2  = (const float*)d_in[11];
    const float* Wr   = (const float*)d_in[12];
    const float* br   = (const float*)d_in[13];
    float* out = (float*)d_out;

    // workspace (~113.4 MB of ~268 MB):
    //   TS   bf16 8*[V][128]  100.7MB  (conv1 uses first half as 8*[V][64])
    //   ACC  bf16 [2][V][64]  12.6MB | Wt1/Wtr/Wt2 bf16 128KB | PART1[32] PART2[32] f32
    unsigned short* TS  = (unsigned short*)d_ws;
    unsigned short* ACC = TS + (size_t)8 * V * 128;
    unsigned short* Wt1 = ACC + (size_t)2 * V * 64;
    unsigned short* Wtr = Wt1 + 8 * 64 * 32;
    unsigned short* Wt2 = Wtr + 8 * 64 * 32;
    float* PART1 = (float*)(Wt2 + 8 * 64 * 64);
    float* PART2 = PART1 + 32;

    prep_k<<<260, 256, 0, stream>>>(W1, Wr, W2, Wt1, Wtr, Wt2, PART1);

    // ---- conv1 basis: T0..T7 in 8 slots of [V][64] bf16 ----
    uint4* T1s[8];
    for (int k = 0; k < 8; ++k) T1s[k] = (uint4*)(TS + (size_t)k * V * 64);

    reorder_k<<<V * 32 / 256, 256, 0, stream>>>(x, (unsigned*)T1s[0]);
    spmm_step<4, true><<<V * 4 / 256, 256, 0, stream>>>(T1s[0], nullptr, T1s[1], vals, col);
    for (int k = 2; k < 8; ++k)
        spmm_step<4, false><<<V * 4 / 256, 256, 0, stream>>>(T1s[k-1], T1s[k-2], T1s[k], vals, col);

    // conv1 + res: one MFMA pass over all 8 T_k
    mfma_gemm<32, 8, 1, true, true, true><<<V / 64, 256, 0, stream>>>(
        TS, Wt1, Wtr, b1, br, ACC, out, PART1);

    // ---- conv2: GN1(h1) as T0; all 8 T_k materialized in distinct slots ----
    uint4* T2s[8];
    for (int k = 0; k < 8; ++k) T2s[k] = (uint4*)(TS + (size_t)k * V * 128);

    gn_apply<<<V * 16 / 256, 256, 0, stream>>>(ACC, PART1, g1, be1, (unsigned*)T2s[0]);
    spmm_step<8, true><<<V * 8 / 256, 256, 0, stream>>>(T2s[0], nullptr, T2s[1], vals, col);
    for (int k = 2; k < 8; ++k)
        spmm_step<8, false><<<V * 8 / 256, 256, 0, stream>>>(T2s[k-1], T2s[k-2], T2s[k], vals, col);

    // conv2: single GEMM, two staging phases (no ACC RMW)
    mfma_gemm<64, 8, 2, false, true, true><<<V / 64, 256, 0, stream>>>(
        TS, Wt2, nullptr, b2, nullptr, ACC, nullptr, PART2);

    final_out<<<2 * V * 8 / 256, 256, 0, stream>>>(ACC, out, PART2, g2, be2);
}